// Round 2
// baseline (3998.271 us; speedup 1.0000x reference)
//
#include <hip/hip_runtime.h>
#include <cstdint>

typedef unsigned short u16;
typedef __bf16 bf16x8 __attribute__((ext_vector_type(8)));
typedef float f32x4 __attribute__((ext_vector_type(4)));

#define L_ 2048
#define S_ 2048
#define B_ 4
#define E_ 1024
#define H_ 16
#define FF_ 4096
#define M_ (L_*B_)

__device__ __forceinline__ unsigned f2bf(float f) {
  unsigned u = __float_as_uint(f);
  return (u + 0x7fffu + ((u >> 16) & 1u)) >> 16;
}
__device__ __forceinline__ float bflo(unsigned u){ return __uint_as_float(u << 16); }
__device__ __forceinline__ float bfhi(unsigned u){ return __uint_as_float(u & 0xffff0000u); }

// ---------------- f32 -> bf16 conversion (4 elems/thread) ----------------
__global__ void cvt_bf16(const float* __restrict__ in, u16* __restrict__ out, int n) {
  int i = (blockIdx.x * blockDim.x + threadIdx.x) << 2;
  if (i >= n) return;
  float4 f = *(const float4*)(in + i);
  uint2 u;
  u.x = f2bf(f.x) | (f2bf(f.y) << 16);
  u.y = f2bf(f.z) | (f2bf(f.w) << 16);
  *(uint2*)(out + i) = u;
}

// ---------------- bf16 GEMM: C[M,N] = A[M,K] @ B[N,K]^T + bias ----------------
// 128x128 tile, 4 waves (2x2), each wave 64x64 via 4x4 mfma_f32_16x16x32_bf16.
__device__ __forceinline__ void gl_lds16(const u16* g, u16* l) {
  __builtin_amdgcn_global_load_lds(
      (const __attribute__((address_space(1))) unsigned int*)g,
      (__attribute__((address_space(3))) unsigned int*)l, 16, 0, 0);
}

template<int RELU>
__global__ __launch_bounds__(256, 2) void gemm_bt(
    const u16* __restrict__ A,
    const u16* __restrict__ Bw,
    const float* __restrict__ bias,
    u16* __restrict__ Cb,
    int K, int N)
{
  __shared__ __align__(16) u16 As[128*32];
  __shared__ __align__(16) u16 Bs[128*32];
  const int tid  = threadIdx.x;
  const int lane = tid & 63;
  const int quad = lane >> 4;
  const int l16  = lane & 15;
  const int wave = tid >> 6;
  const int wm = (wave & 1) << 6;
  const int wn = (wave >> 1) << 6;
  const int bm = blockIdx.y << 7;
  const int bn = blockIdx.x << 7;

  // staging: thread tid covers LDS elems [tid*8, tid*8+8) and [tid*8+2048, ...)
  const int e0 = tid << 3;
  const int r0 = e0 >> 5;
  const int c0 = e0 & 31;
  const u16* a0 = A  + (size_t)(bm + r0)      * K + c0;
  const u16* a1 = A  + (size_t)(bm + r0 + 64) * K + c0;
  const u16* b0 = Bw + (size_t)(bn + r0)      * K + c0;
  const u16* b1 = Bw + (size_t)(bn + r0 + 64) * K + c0;

  f32x4 acc[4][4];
  #pragma unroll
  for (int i = 0; i < 4; i++)
    #pragma unroll
    for (int j = 0; j < 4; j++)
      acc[i][j] = (f32x4){0.f, 0.f, 0.f, 0.f};

  for (int k0 = 0; k0 < K; k0 += 32) {
    __syncthreads();
    gl_lds16(a0, As + e0);
    gl_lds16(a1, As + e0 + 2048);
    gl_lds16(b0, Bs + e0);
    gl_lds16(b1, Bs + e0 + 2048);
    a0 += 32; a1 += 32; b0 += 32; b1 += 32;
    __syncthreads();

    bf16x8 af[4], bfv[4];
    #pragma unroll
    for (int t = 0; t < 4; t++) {
      af[t]  = *(const bf16x8*)(As + ((wm + t*16 + l16) << 5) + (quad << 3));
      bfv[t] = *(const bf16x8*)(Bs + ((wn + t*16 + l16) << 5) + (quad << 3));
    }
    #pragma unroll
    for (int mt = 0; mt < 4; mt++)
      #pragma unroll
      for (int nt = 0; nt < 4; nt++)
        acc[mt][nt] = __builtin_amdgcn_mfma_f32_16x16x32_bf16(af[mt], bfv[nt], acc[mt][nt], 0, 0, 0);
  }

  #pragma unroll
  for (int nt = 0; nt < 4; nt++) {
    const int col = bn + wn + nt*16 + l16;
    const float bv = bias[col];
    #pragma unroll
    for (int mt = 0; mt < 4; mt++) {
      #pragma unroll
      for (int i = 0; i < 4; i++) {
        const int row = bm + wm + mt*16 + quad*4 + i;
        float v = acc[mt][nt][i] + bv;
        if (RELU) v = fmaxf(v, 0.0f);
        Cb[(size_t)row * N + col] = (u16)f2bf(v);
      }
    }
  }
}

// ---------------- flash attention (vector f32), 128 q-rows per block ----------------
// Q/K/V/O layout: (seq*B_, E_) with row = l*B_ + b, head h at cols [h*64, h*64+64)
// O may alias Q: each thread reads its own Q fully into registers before any write.
template<int CAUSAL>
__global__ __launch_bounds__(128, 2) void attn(
    const u16* __restrict__ Q,
    const u16* __restrict__ Kg,
    const u16* __restrict__ Vg,
    u16* __restrict__ O,
    int Skv)
{
  __shared__ __align__(16) float Ks[64*68];
  __shared__ __align__(16) float Vs[64*68];
  const int tid = threadIdx.x;
  const int bh = blockIdx.y;
  const int b = bh >> 4;
  const int h = bh & 15;
  const int q0 = blockIdx.x << 7;
  const int qrow = q0 + tid;
  const size_t qoff = ((size_t)qrow * B_ + b) * E_ + h * 64;

  float q[64], o[64];
  #pragma unroll
  for (int d = 0; d < 64; d += 8) {
    uint4 u = *(const uint4*)(Q + qoff + d);
    q[d+0] = bflo(u.x); q[d+1] = bfhi(u.x);
    q[d+2] = bflo(u.y); q[d+3] = bfhi(u.y);
    q[d+4] = bflo(u.z); q[d+5] = bfhi(u.z);
    q[d+6] = bflo(u.w); q[d+7] = bfhi(u.w);
  }
  #pragma unroll
  for (int d = 0; d < 64; d++) o[d] = 0.0f;
  float mrun = -1e30f, lsum = 0.0f;

  const int send = CAUSAL ? (q0 + 128) : Skv;
  const int sQ = tid >> 5;            // 0..3
  const int dPair = (tid & 31) << 1;  // 0..62

  for (int s0 = 0; s0 < send; s0 += 64) {
    __syncthreads();
    #pragma unroll
    for (int it = 0; it < 16; it++) {
      const int s = (it << 2) + sQ;
      const size_t goff = ((size_t)(s0 + s) * B_ + b) * E_ + h * 64 + dPair;
      unsigned ku = *(const unsigned*)(Kg + goff);
      unsigned vu = *(const unsigned*)(Vg + goff);
      Ks[s*68 + dPair]     = bflo(ku);
      Ks[s*68 + dPair + 1] = bfhi(ku);
      Vs[s*68 + dPair]     = bflo(vu);
      Vs[s*68 + dPair + 1] = bfhi(vu);
    }
    __syncthreads();

    #pragma unroll 1
    for (int s = 0; s < 64; s++) {
      float d0 = 0.f, d1 = 0.f, d2 = 0.f, d3 = 0.f;
      #pragma unroll
      for (int d = 0; d < 64; d += 4) {
        f32x4 k4 = *(const f32x4*)(Ks + s*68 + d);
        d0 = fmaf(q[d+0], k4[0], d0);
        d1 = fmaf(q[d+1], k4[1], d1);
        d2 = fmaf(q[d+2], k4[2], d2);
        d3 = fmaf(q[d+3], k4[3], d3);
      }
      float sc = ((d0 + d1) + (d2 + d3)) * 0.125f;
      if (CAUSAL) sc = (s0 + s <= qrow) ? sc : -1e30f;
      float mn = fmaxf(mrun, sc);
      if (mn > mrun) {
        float alpha = __expf(mrun - mn);
        lsum *= alpha;
        #pragma unroll
        for (int d = 0; d < 64; d++) o[d] *= alpha;
        mrun = mn;
      }
      float w = __expf(sc - mrun);
      lsum += w;
      #pragma unroll
      for (int d = 0; d < 64; d += 4) {
        f32x4 v4 = *(const f32x4*)(Vs + s*68 + d);
        o[d+0] = fmaf(w, v4[0], o[d+0]);
        o[d+1] = fmaf(w, v4[1], o[d+1]);
        o[d+2] = fmaf(w, v4[2], o[d+2]);
        o[d+3] = fmaf(w, v4[3], o[d+3]);
      }
    }
  }

  const float inv = 1.0f / lsum;
  #pragma unroll
  for (int d = 0; d < 64; d += 2) {
    unsigned pk = f2bf(o[d] * inv) | (f2bf(o[d+1] * inv) << 16);
    *(unsigned*)(O + qoff + d) = pk;
  }
}

// ---------------- residual add + LayerNorm (one row of 1024 per block) ----------------
// X bf16; residual R either f32 (RF32=1) or bf16; output f32 and/or bf16.
// outB may alias Rb (same-index read-before-write per thread).
template<int RF32>
__global__ __launch_bounds__(256) void add_ln(
    const u16* __restrict__ X,
    const float* __restrict__ Rf, const u16* __restrict__ Rb,
    const float* __restrict__ g, const float* __restrict__ be,
    float* __restrict__ outF, u16* __restrict__ outB)
{
  const int row = blockIdx.x;
  const int tid = threadIdx.x;
  const size_t base = (size_t)row * E_;
  uint2 xu = *(const uint2*)(X + base + tid*4);
  float x0 = bflo(xu.x), x1 = bfhi(xu.x), x2 = bflo(xu.y), x3 = bfhi(xu.y);
  float r0, r1, r2, r3;
  if (RF32) {
    float4 rv = *(const float4*)(Rf + base + tid*4);
    r0 = rv.x; r1 = rv.y; r2 = rv.z; r3 = rv.w;
  } else {
    uint2 ru = *(const uint2*)(Rb + base + tid*4);
    r0 = bflo(ru.x); r1 = bfhi(ru.x); r2 = bflo(ru.y); r3 = bfhi(ru.y);
  }
  const float v0 = x0 + r0, v1 = x1 + r1, v2 = x2 + r2, v3 = x3 + r3;
  float s  = v0 + v1 + v2 + v3;
  float s2 = v0*v0 + v1*v1 + v2*v2 + v3*v3;
  #pragma unroll
  for (int off = 32; off >= 1; off >>= 1) {
    s  += __shfl_down(s,  off);
    s2 += __shfl_down(s2, off);
  }
  __shared__ float ps[4], ps2[4];
  const int wv = tid >> 6, lane = tid & 63;
  if (lane == 0) { ps[wv] = s; ps2[wv] = s2; }
  __syncthreads();
  const float ts  = ps[0] + ps[1] + ps[2] + ps[3];
  const float ts2 = ps2[0] + ps2[1] + ps2[2] + ps2[3];
  const float mu  = ts * (1.0f / E_);
  const float var = ts2 * (1.0f / E_) - mu * mu;
  const float rs  = rsqrtf(var + 1e-5f);
  float4 gv = *(const float4*)(g  + tid*4);
  float4 bv = *(const float4*)(be + tid*4);
  const float o0 = (v0 - mu) * rs * gv.x + bv.x;
  const float o1 = (v1 - mu) * rs * gv.y + bv.y;
  const float o2 = (v2 - mu) * rs * gv.z + bv.z;
  const float o3 = (v3 - mu) * rs * gv.w + bv.w;
  if (outF) {
    float4 ov; ov.x = o0; ov.y = o1; ov.z = o2; ov.w = o3;
    *(float4*)(outF + base + tid*4) = ov;
  }
  if (outB) {
    uint2 u;
    u.x = f2bf(o0) | (f2bf(o1) << 16);
    u.y = f2bf(o2) | (f2bf(o3) << 16);
    *(uint2*)(outB + base + tid*4) = u;
  }
}

// ---------------- driver ----------------
extern "C" void kernel_launch(void* const* d_in, const int* in_sizes, int n_in,
                              void* d_out, int out_size, void* d_ws, size_t ws_size,
                              hipStream_t stream) {
  (void)in_sizes; (void)n_in; (void)out_size; (void)ws_size;
  const float* tgt  = (const float*)d_in[0];
  const float* mem  = (const float*)d_in[1];
  const float* saWq = (const float*)d_in[3];  const float* sabq = (const float*)d_in[4];
  const float* saWk = (const float*)d_in[5];  const float* sabk = (const float*)d_in[6];
  const float* saWv = (const float*)d_in[7];  const float* sabv = (const float*)d_in[8];
  const float* saWo = (const float*)d_in[9];  const float* sabo = (const float*)d_in[10];
  const float* caWq = (const float*)d_in[11]; const float* cabq = (const float*)d_in[12];
  const float* caWk = (const float*)d_in[13]; const float* cabk = (const float*)d_in[14];
  const float* caWv = (const float*)d_in[15]; const float* cabv = (const float*)d_in[16];
  const float* caWo = (const float*)d_in[17]; const float* cabo = (const float*)d_in[18];
  const float* W1   = (const float*)d_in[19]; const float* b1   = (const float*)d_in[20];
  const float* W2   = (const float*)d_in[21]; const float* b2   = (const float*)d_in[22];
  const float* ln1g = (const float*)d_in[23]; const float* ln1b = (const float*)d_in[24];
  const float* ln2g = (const float*)d_in[25]; const float* ln2b = (const float*)d_in[26];
  const float* ln3g = (const float*)d_in[27]; const float* ln3b = (const float*)d_in[28];
  float* out = (float*)d_out;

  // Workspace layout (bf16 u16 buffers), 16 MB units; peak = 104 MB.
  //  A (0-16M):   tgt_bf16 -> x1 -> x2 (ln writes alias residual in-place)
  //  Cq(16-32M):  q (attn writes output in-place over q)
  //  Bm(32-48M):  memory_bf16
  //  Dk(48-64M):  k
  //  Ev(64-80M):  v
  //  Ff(80-96M):  per-stage GEMM output (attn-proj / ffn2), ln X input
  //  wS(96-104M): shared weight bf16 staging (max FF_*E_)
  //  hb = Cq..Ev (16-80M, 64 MB) FFN hidden, overlays dead q/mem/k/v
  char* wsp = (char*)d_ws;
  const size_t MB16 = (size_t)16 * 1024 * 1024;
  u16* A  = (u16*)(wsp + 0 * MB16);
  u16* Cq = (u16*)(wsp + 1 * MB16);
  u16* Bm = (u16*)(wsp + 2 * MB16);
  u16* Dk = (u16*)(wsp + 3 * MB16);
  u16* Ev = (u16*)(wsp + 4 * MB16);
  u16* Ff = (u16*)(wsp + 5 * MB16);
  u16* wS = (u16*)(wsp + 6 * MB16);
  u16* hb = Cq;

  const int CT = 256;
  dim3 blk(256);
  dim3 g8(E_/128, M_/128);    // N=1024
  dim3 g32(FF_/128, M_/128);  // N=4096
  dim3 ga(L_/128, B_*H_);
  auto cvt = [&](const float* src, u16* dst, int n) {
    cvt_bf16<<<n/(4*CT), CT, 0, stream>>>(src, dst, n);
  };

  cvt(tgt, A,  M_*E_);
  cvt(mem, Bm, M_*E_);

  // ---- self-attention ----
  cvt(saWq, wS, E_*E_); gemm_bt<0><<<g8, blk, 0, stream>>>(A, wS, sabq, Cq, E_, E_);
  cvt(saWk, wS, E_*E_); gemm_bt<0><<<g8, blk, 0, stream>>>(A, wS, sabk, Dk, E_, E_);
  cvt(saWv, wS, E_*E_); gemm_bt<0><<<g8, blk, 0, stream>>>(A, wS, sabv, Ev, E_, E_);
  attn<1><<<ga, dim3(128), 0, stream>>>(Cq, Dk, Ev, Cq, S_);
  cvt(saWo, wS, E_*E_); gemm_bt<0><<<g8, blk, 0, stream>>>(Cq, wS, sabo, Ff, E_, E_);
  add_ln<1><<<M_, blk, 0, stream>>>(Ff, tgt, nullptr, ln1g, ln1b, nullptr, A);

  // ---- cross-attention ----
  cvt(caWq, wS, E_*E_); gemm_bt<0><<<g8, blk, 0, stream>>>(A,  wS, cabq, Cq, E_, E_);
  cvt(caWk, wS, E_*E_); gemm_bt<0><<<g8, blk, 0, stream>>>(Bm, wS, cabk, Dk, E_, E_);
  cvt(caWv, wS, E_*E_); gemm_bt<0><<<g8, blk, 0, stream>>>(Bm, wS, cabv, Ev, E_, E_);
  attn<0><<<ga, dim3(128), 0, stream>>>(Cq, Dk, Ev, Cq, S_);
  cvt(caWo, wS, E_*E_); gemm_bt<0><<<g8, blk, 0, stream>>>(Cq, wS, cabo, Ff, E_, E_);
  add_ln<0><<<M_, blk, 0, stream>>>(Ff, nullptr, A, ln2g, ln2b, nullptr, A);

  // ---- FFN ----
  cvt(W1, wS, FF_*E_); gemm_bt<1><<<g32, blk, 0, stream>>>(A, wS, b1, hb, E_, FF_);
  cvt(W2, wS, FF_*E_); gemm_bt<0><<<g8, blk, 0, stream>>>(hb, wS, b2, Ff, FF_, E_);
  add_ln<0><<<M_, blk, 0, stream>>>(Ff, nullptr, A, ln3g, ln3b, out, nullptr);
}

// Round 3
// 1014.211 us; speedup vs baseline: 3.9422x; 3.9422x over previous
//
#include <hip/hip_runtime.h>
#include <cstdint>

typedef unsigned short u16;
typedef __bf16 bf16x8 __attribute__((ext_vector_type(8)));
typedef float f32x4 __attribute__((ext_vector_type(4)));

#define L_ 2048
#define S_ 2048
#define B_ 4
#define E_ 1024
#define H_ 16
#define FF_ 4096
#define M_ (L_*B_)

__device__ __forceinline__ unsigned f2bf(float f) {
  unsigned u = __float_as_uint(f);
  return (u + 0x7fffu + ((u >> 16) & 1u)) >> 16;
}
__device__ __forceinline__ float bflo(unsigned u){ return __uint_as_float(u << 16); }
__device__ __forceinline__ float bfhi(unsigned u){ return __uint_as_float(u & 0xffff0000u); }

// ---------------- f32 -> bf16 conversion (4 elems/thread) ----------------
__global__ void cvt_bf16(const float* __restrict__ in, u16* __restrict__ out, int n) {
  int i = (blockIdx.x * blockDim.x + threadIdx.x) << 2;
  if (i >= n) return;
  float4 f = *(const float4*)(in + i);
  uint2 u;
  u.x = f2bf(f.x) | (f2bf(f.y) << 16);
  u.y = f2bf(f.z) | (f2bf(f.w) << 16);
  *(uint2*)(out + i) = u;
}

// ---------------- bf16 GEMM: C[M,N] = A[M,K] @ B[N,K]^T + bias ----------------
__device__ __forceinline__ void gl_lds16(const u16* g, u16* l) {
  __builtin_amdgcn_global_load_lds(
      (const __attribute__((address_space(1))) unsigned int*)g,
      (__attribute__((address_space(3))) unsigned int*)l, 16, 0, 0);
}

template<int RELU>
__global__ __launch_bounds__(256, 2) void gemm_bt(
    const u16* __restrict__ A,
    const u16* __restrict__ Bw,
    const float* __restrict__ bias,
    u16* __restrict__ Cb,
    int K, int N)
{
  __shared__ __align__(16) u16 As[128*32];
  __shared__ __align__(16) u16 Bs[128*32];
  const int tid  = threadIdx.x;
  const int lane = tid & 63;
  const int quad = lane >> 4;
  const int l16  = lane & 15;
  const int wave = tid >> 6;
  const int wm = (wave & 1) << 6;
  const int wn = (wave >> 1) << 6;
  const int bm = blockIdx.y << 7;
  const int bn = blockIdx.x << 7;

  const int e0 = tid << 3;
  const int r0 = e0 >> 5;
  const int c0 = e0 & 31;
  const u16* a0 = A  + (size_t)(bm + r0)      * K + c0;
  const u16* a1 = A  + (size_t)(bm + r0 + 64) * K + c0;
  const u16* b0 = Bw + (size_t)(bn + r0)      * K + c0;
  const u16* b1 = Bw + (size_t)(bn + r0 + 64) * K + c0;

  f32x4 acc[4][4];
  #pragma unroll
  for (int i = 0; i < 4; i++)
    #pragma unroll
    for (int j = 0; j < 4; j++)
      acc[i][j] = (f32x4){0.f, 0.f, 0.f, 0.f};

  for (int k0 = 0; k0 < K; k0 += 32) {
    __syncthreads();
    gl_lds16(a0, As + e0);
    gl_lds16(a1, As + e0 + 2048);
    gl_lds16(b0, Bs + e0);
    gl_lds16(b1, Bs + e0 + 2048);
    a0 += 32; a1 += 32; b0 += 32; b1 += 32;
    __syncthreads();

    bf16x8 af[4], bfv[4];
    #pragma unroll
    for (int t = 0; t < 4; t++) {
      af[t]  = *(const bf16x8*)(As + ((wm + t*16 + l16) << 5) + (quad << 3));
      bfv[t] = *(const bf16x8*)(Bs + ((wn + t*16 + l16) << 5) + (quad << 3));
    }
    #pragma unroll
    for (int mt = 0; mt < 4; mt++)
      #pragma unroll
      for (int nt = 0; nt < 4; nt++)
        acc[mt][nt] = __builtin_amdgcn_mfma_f32_16x16x32_bf16(af[mt], bfv[nt], acc[mt][nt], 0, 0, 0);
  }

  #pragma unroll
  for (int nt = 0; nt < 4; nt++) {
    const int col = bn + wn + nt*16 + l16;
    const float bv = bias[col];
    #pragma unroll
    for (int mt = 0; mt < 4; mt++) {
      #pragma unroll
      for (int i = 0; i < 4; i++) {
        const int row = bm + wm + mt*16 + quad*4 + i;
        float v = acc[mt][nt][i] + bv;
        if (RELU) v = fmaxf(v, 0.0f);
        Cb[(size_t)row * N + col] = (u16)f2bf(v);
      }
    }
  }
}

// ---------------- V transpose: V[(l*B+b)][h*64+d] -> Vt[(b*16+h)*64+d][l] ----------------
// Writes are fully coalesced (64 consecutive l per instruction).
__global__ __launch_bounds__(256) void transpose_v(
    const u16* __restrict__ V, u16* __restrict__ Vt)
{
  const int t = threadIdx.x;
  const int lane = t & 63;
  const int w = t >> 6;
  const int bh = blockIdx.y;
  const int b = bh >> 4, h = bh & 15;
  const int l = (blockIdx.x << 6) + lane;
  const size_t vrow = ((size_t)l * B_ + b) * E_ + h * 64;
  #pragma unroll
  for (int g = 0; g < 2; g++) {
    const int d0 = w * 8 + g * 32;
    uint4 u = *(const uint4*)(V + vrow + d0);
    u16 e[8];
    e[0] = u.x & 0xffff; e[1] = u.x >> 16;
    e[2] = u.y & 0xffff; e[3] = u.y >> 16;
    e[4] = u.z & 0xffff; e[5] = u.z >> 16;
    e[6] = u.w & 0xffff; e[7] = u.w >> 16;
    #pragma unroll
    for (int j = 0; j < 8; j++)
      Vt[(size_t)(bh * 64 + d0 + j) * S_ + l] = e[j];
  }
}

// ---------------- MFMA flash attention ----------------
// Block: 256 thr = 4 waves; each wave owns 16 q-rows (Br=64). KV tile Bc=64.
// S^T = K @ Q^T  (A=K-frag, B=Q-frag): C/D lane holds q=lane&15 (one row's state),
// s = quad*4+reg per 16-s tile -> softmax: lane-local reduce + 2 shfl_xor.
// P -> wave-private LDS [q][s] (stride 72), reload as A-frag; B-frag = Vt tile.
// O C/D: lane holds d=lane&15, q=quad*4+reg; alpha/l fetched by __shfl.
// O may alias Q (Q frags loaded before any write; blocks own disjoint rows).
template<int CAUSAL>
__global__ __launch_bounds__(256, 2) void attn_mfma(
    const u16* __restrict__ Q,
    const u16* __restrict__ Kg,
    const u16* __restrict__ Vt,
    u16* __restrict__ O,
    int Skv)
{
  __shared__ __align__(16) u16 Ks[64*72];
  __shared__ __align__(16) u16 Vs[64*72];
  __shared__ __align__(16) u16 Ps[4*16*72];
  const int tid  = threadIdx.x;
  const int lane = tid & 63;
  const int w    = tid >> 6;
  const int l16  = lane & 15;
  const int quad = lane >> 4;
  const int bh = blockIdx.y;
  const int b = bh >> 4, h = bh & 15;
  const int q0 = (CAUSAL ? ((int)gridDim.x - 1 - (int)blockIdx.x) : (int)blockIdx.x) << 6;
  const int qrow = q0 + w*16 + l16;            // this lane's softmax q-row

  // Q B-frag (n=q=l16, k=d=kh*32+quad*8+j), from global, once.
  bf16x8 qf[2];
  {
    const size_t qoff = ((size_t)qrow * B_ + b) * E_ + h*64;
    qf[0] = *(const bf16x8*)(Q + qoff + quad*8);
    qf[1] = *(const bf16x8*)(Q + qoff + 32 + quad*8);
  }

  f32x4 oacc[4];
  #pragma unroll
  for (int i = 0; i < 4; i++) oacc[i] = (f32x4){0.f,0.f,0.f,0.f};
  float mrun = -3e38f, lsum = 0.f;
  const float SC = 0.125f * 1.44269504f;       // 1/sqrt(64) * log2(e)

  const int sr = tid >> 3;                      // 0..31
  const int sc = (tid & 7) << 3;                // 0..56
  u16* ps = Ps + w * 16 * 72;

  const int send = CAUSAL ? (q0 + 64) : Skv;
  for (int s0 = 0; s0 < send; s0 += 64) {
    // ---- stage K-tile [s][d] and Vt-tile [d][s] into padded LDS ----
    uint4 k0 = *(const uint4*)(Kg + ((size_t)(s0+sr)    * B_ + b) * E_ + h*64 + sc);
    uint4 k1 = *(const uint4*)(Kg + ((size_t)(s0+sr+32) * B_ + b) * E_ + h*64 + sc);
    uint4 v0 = *(const uint4*)(Vt + (size_t)(bh*64 + sr)      * Skv + s0 + sc);
    uint4 v1 = *(const uint4*)(Vt + (size_t)(bh*64 + sr + 32) * Skv + s0 + sc);
    __syncthreads();   // prior iteration's LDS reads done
    *(uint4*)(Ks + sr*72 + sc)        = k0;
    *(uint4*)(Ks + (sr+32)*72 + sc)   = k1;
    *(uint4*)(Vs + sr*72 + sc)        = v0;
    *(uint4*)(Vs + (sr+32)*72 + sc)   = v1;
    __syncthreads();

    // ---- S^T tiles: sacc[st][r] -> s = s0 + st*16 + quad*4 + r, q = l16 ----
    f32x4 sacc[4];
    #pragma unroll
    for (int st = 0; st < 4; st++) sacc[st] = (f32x4){0.f,0.f,0.f,0.f};
    #pragma unroll
    for (int kh = 0; kh < 2; kh++) {
      #pragma unroll
      for (int st = 0; st < 4; st++) {
        bf16x8 kf = *(const bf16x8*)(Ks + (st*16 + l16)*72 + kh*32 + quad*8);
        sacc[st] = __builtin_amdgcn_mfma_f32_16x16x32_bf16(kf, qf[kh], sacc[st], 0, 0, 0);
      }
    }

    // ---- online softmax (base-2), per-lane row state ----
    float p[16];
    float mx = -3e38f;
    #pragma unroll
    for (int st = 0; st < 4; st++) {
      #pragma unroll
      for (int r = 0; r < 4; r++) {
        float sv = sacc[st][r] * SC;
        if (CAUSAL) sv = (s0 + st*16 + quad*4 + r <= qrow) ? sv : -3e38f;
        p[st*4+r] = sv;
        mx = fmaxf(mx, sv);
      }
    }
    mx = fmaxf(mx, __shfl_xor(mx, 16));
    mx = fmaxf(mx, __shfl_xor(mx, 32));
    const float mnew = fmaxf(mrun, mx);
    const float alpha = exp2f(mrun - mnew);
    float rs = 0.f;
    #pragma unroll
    for (int i = 0; i < 16; i++) { p[i] = exp2f(p[i] - mnew); rs += p[i]; }
    rs += __shfl_xor(rs, 16);
    rs += __shfl_xor(rs, 32);
    lsum = lsum * alpha + rs;
    mrun = mnew;

    // ---- rescale O (O rows are q = quad*4+r; alpha lives at lane q) ----
    #pragma unroll
    for (int r = 0; r < 4; r++) {
      const float ar = __shfl(alpha, (quad << 2) + r);
      #pragma unroll
      for (int dt = 0; dt < 4; dt++) oacc[dt][r] *= ar;
    }

    // ---- store P to wave-private LDS [q=l16][s] (bf16, packed pairs) ----
    #pragma unroll
    for (int st = 0; st < 4; st++) {
      unsigned pk0 = f2bf(p[st*4+0]) | (f2bf(p[st*4+1]) << 16);
      unsigned pk1 = f2bf(p[st*4+2]) | (f2bf(p[st*4+3]) << 16);
      *(unsigned*)(ps + l16*72 + st*16 + quad*4)     = pk0;
      *(unsigned*)(ps + l16*72 + st*16 + quad*4 + 2) = pk1;
    }

    // ---- PV: oacc[dt] += P[16q x 64s] @ V[64s x 16d] ----
    #pragma unroll
    for (int kh = 0; kh < 2; kh++) {
      bf16x8 pf = *(const bf16x8*)(ps + l16*72 + kh*32 + quad*8);
      #pragma unroll
      for (int dt = 0; dt < 4; dt++) {
        bf16x8 vf = *(const bf16x8*)(Vs + (dt*16 + l16)*72 + kh*32 + quad*8);
        oacc[dt] = __builtin_amdgcn_mfma_f32_16x16x32_bf16(pf, vf, oacc[dt], 0, 0, 0);
      }
    }
  }

  // ---- epilogue: O[q][d], lane holds d = dt*16+l16, q = q0+w*16+quad*4+r ----
  #pragma unroll
  for (int r = 0; r < 4; r++) {
    const float li = 1.0f / __shfl(lsum, (quad << 2) + r);
    const int qg = q0 + w*16 + quad*4 + r;
    const size_t orow = ((size_t)qg * B_ + b) * E_ + h*64;
    #pragma unroll
    for (int dt = 0; dt < 4; dt++)
      O[orow + dt*16 + l16] = (u16)f2bf(oacc[dt][r] * li);
  }
}

// ---------------- residual add + LayerNorm ----------------
template<int RF32>
__global__ __launch_bounds__(256) void add_ln(
    const u16* __restrict__ X,
    const float* __restrict__ Rf, const u16* __restrict__ Rb,
    const float* __restrict__ g, const float* __restrict__ be,
    float* __restrict__ outF, u16* __restrict__ outB)
{
  const int row = blockIdx.x;
  const int tid = threadIdx.x;
  const size_t base = (size_t)row * E_;
  uint2 xu = *(const uint2*)(X + base + tid*4);
  float x0 = bflo(xu.x), x1 = bfhi(xu.x), x2 = bflo(xu.y), x3 = bfhi(xu.y);
  float r0, r1, r2, r3;
  if (RF32) {
    float4 rv = *(const float4*)(Rf + base + tid*4);
    r0 = rv.x; r1 = rv.y; r2 = rv.z; r3 = rv.w;
  } else {
    uint2 ru = *(const uint2*)(Rb + base + tid*4);
    r0 = bflo(ru.x); r1 = bfhi(ru.x); r2 = bflo(ru.y); r3 = bfhi(ru.y);
  }
  const float v0 = x0 + r0, v1 = x1 + r1, v2 = x2 + r2, v3 = x3 + r3;
  float s  = v0 + v1 + v2 + v3;
  float s2 = v0*v0 + v1*v1 + v2*v2 + v3*v3;
  #pragma unroll
  for (int off = 32; off >= 1; off >>= 1) {
    s  += __shfl_down(s,  off);
    s2 += __shfl_down(s2, off);
  }
  __shared__ float ps[4], ps2[4];
  const int wv = tid >> 6, lane = tid & 63;
  if (lane == 0) { ps[wv] = s; ps2[wv] = s2; }
  __syncthreads();
  const float ts  = ps[0] + ps[1] + ps[2] + ps[3];
  const float ts2 = ps2[0] + ps2[1] + ps2[2] + ps2[3];
  const float mu  = ts * (1.0f / E_);
  const float var = ts2 * (1.0f / E_) - mu * mu;
  const float rsq = rsqrtf(var + 1e-5f);
  float4 gv = *(const float4*)(g  + tid*4);
  float4 bv = *(const float4*)(be + tid*4);
  const float o0 = (v0 - mu) * rsq * gv.x + bv.x;
  const float o1 = (v1 - mu) * rsq * gv.y + bv.y;
  const float o2 = (v2 - mu) * rsq * gv.z + bv.z;
  const float o3 = (v3 - mu) * rsq * gv.w + bv.w;
  if (outF) {
    float4 ov; ov.x = o0; ov.y = o1; ov.z = o2; ov.w = o3;
    *(float4*)(outF + base + tid*4) = ov;
  }
  if (outB) {
    uint2 u;
    u.x = f2bf(o0) | (f2bf(o1) << 16);
    u.y = f2bf(o2) | (f2bf(o3) << 16);
    *(uint2*)(outB + base + tid*4) = u;
  }
}

// ---------------- driver ----------------
extern "C" void kernel_launch(void* const* d_in, const int* in_sizes, int n_in,
                              void* d_out, int out_size, void* d_ws, size_t ws_size,
                              hipStream_t stream) {
  (void)in_sizes; (void)n_in; (void)out_size; (void)ws_size;
  const float* tgt  = (const float*)d_in[0];
  const float* mem  = (const float*)d_in[1];
  const float* saWq = (const float*)d_in[3];  const float* sabq = (const float*)d_in[4];
  const float* saWk = (const float*)d_in[5];  const float* sabk = (const float*)d_in[6];
  const float* saWv = (const float*)d_in[7];  const float* sabv = (const float*)d_in[8];
  const float* saWo = (const float*)d_in[9];  const float* sabo = (const float*)d_in[10];
  const float* caWq = (const float*)d_in[11]; const float* cabq = (const float*)d_in[12];
  const float* caWk = (const float*)d_in[13]; const float* cabk = (const float*)d_in[14];
  const float* caWv = (const float*)d_in[15]; const float* cabv = (const float*)d_in[16];
  const float* caWo = (const float*)d_in[17]; const float* cabo = (const float*)d_in[18];
  const float* W1   = (const float*)d_in[19]; const float* b1   = (const float*)d_in[20];
  const float* W2   = (const float*)d_in[21]; const float* b2   = (const float*)d_in[22];
  const float* ln1g = (const float*)d_in[23]; const float* ln1b = (const float*)d_in[24];
  const float* ln2g = (const float*)d_in[25]; const float* ln2b = (const float*)d_in[26];
  const float* ln3g = (const float*)d_in[27]; const float* ln3b = (const float*)d_in[28];
  float* out = (float*)d_out;

  // Workspace layout (16 MB slots), peak 104 MB:
  //  A:  tgt_bf16 -> x1 -> x2   Cq: q / attn-out (in-place)   Bm: memory_bf16
  //  Dk: k                      Ev: v                          Ff: Vt -> gemm out / ln X
  //  wS: weight bf16 staging (8 MB)                            hb = Cq..Ev (FFN hidden)
  char* wsp = (char*)d_ws;
  const size_t MB16 = (size_t)16 * 1024 * 1024;
  u16* A  = (u16*)(wsp + 0 * MB16);
  u16* Cq = (u16*)(wsp + 1 * MB16);
  u16* Bm = (u16*)(wsp + 2 * MB16);
  u16* Dk = (u16*)(wsp + 3 * MB16);
  u16* Ev = (u16*)(wsp + 4 * MB16);
  u16* Ff = (u16*)(wsp + 5 * MB16);
  u16* wS = (u16*)(wsp + 6 * MB16);
  u16* hb = Cq;

  const int CT = 256;
  dim3 blk(256);
  dim3 g8(E_/128, M_/128);
  dim3 g32(FF_/128, M_/128);
  dim3 ga(L_/64, B_*H_);
  dim3 gt(S_/64, B_*H_);
  auto cvt = [&](const float* src, u16* dst, int n) {
    cvt_bf16<<<n/(4*CT), CT, 0, stream>>>(src, dst, n);
  };

  cvt(tgt, A,  M_*E_);
  cvt(mem, Bm, M_*E_);

  // ---- self-attention ----
  cvt(saWq, wS, E_*E_); gemm_bt<0><<<g8, blk, 0, stream>>>(A, wS, sabq, Cq, E_, E_);
  cvt(saWk, wS, E_*E_); gemm_bt<0><<<g8, blk, 0, stream>>>(A, wS, sabk, Dk, E_, E_);
  cvt(saWv, wS, E_*E_); gemm_bt<0><<<g8, blk, 0, stream>>>(A, wS, sabv, Ev, E_, E_);
  transpose_v<<<gt, blk, 0, stream>>>(Ev, Ff);
  attn_mfma<1><<<ga, blk, 0, stream>>>(Cq, Dk, Ff, Cq, S_);
  cvt(saWo, wS, E_*E_); gemm_bt<0><<<g8, blk, 0, stream>>>(Cq, wS, sabo, Ff, E_, E_);
  add_ln<1><<<M_, blk, 0, stream>>>(Ff, tgt, nullptr, ln1g, ln1b, nullptr, A);

  // ---- cross-attention ----
  cvt(caWq, wS, E_*E_); gemm_bt<0><<<g8, blk, 0, stream>>>(A,  wS, cabq, Cq, E_, E_);
  cvt(caWk, wS, E_*E_); gemm_bt<0><<<g8, blk, 0, stream>>>(Bm, wS, cabk, Dk, E_, E_);
  cvt(caWv, wS, E_*E_); gemm_bt<0><<<g8, blk, 0, stream>>>(Bm, wS, cabv, Ev, E_, E_);
  transpose_v<<<gt, blk, 0, stream>>>(Ev, Ff);
  attn_mfma<0><<<ga, blk, 0, stream>>>(Cq, Dk, Ff, Cq, S_);
  cvt(caWo, wS, E_*E_); gemm_bt<0><<<g8, blk, 0, stream>>>(Cq, wS, cabo, Ff, E_, E_);
  add_ln<0><<<M_, blk, 0, stream>>>(Ff, nullptr, A, ln2g, ln2b, nullptr, A);

  // ---- FFN ----
  cvt(W1, wS, FF_*E_); gemm_bt<1><<<g32, blk, 0, stream>>>(A, wS, b1, hb, E_, FF_);
  cvt(W2, wS, FF_*E_); gemm_bt<0><<<g8, blk, 0, stream>>>(hb, wS, b2, Ff, FF_, E_);
  add_ln<0><<<M_, blk, 0, stream>>>(Ff, nullptr, A, ln3g, ln3b, out, nullptr);
}

// Round 4
// 944.194 us; speedup vs baseline: 4.2346x; 1.0742x over previous
//
#include <hip/hip_runtime.h>
#include <cstdint>

typedef unsigned short u16;
typedef __bf16 bf16x8 __attribute__((ext_vector_type(8)));
typedef float f32x4 __attribute__((ext_vector_type(4)));

#define L_ 2048
#define S_ 2048
#define B_ 4
#define E_ 1024
#define H_ 16
#define FF_ 4096
#define M_ (L_*B_)

#define QK_SCALE 0.18033688f   /* 1/sqrt(64) * log2(e) */

__device__ __forceinline__ unsigned f2bf(float f) {
  unsigned u = __float_as_uint(f);
  return (u + 0x7fffu + ((u >> 16) & 1u)) >> 16;
}
__device__ __forceinline__ float bflo(unsigned u){ return __uint_as_float(u << 16); }
__device__ __forceinline__ float bfhi(unsigned u){ return __uint_as_float(u & 0xffff0000u); }

// ---------------- batched f32 -> bf16 conversion ----------------
// Each block handles 1024 elems entirely inside one segment (all segment
// sizes are multiples of 1024). Linear scalar scan to find the segment.
struct CvtSeg { const float* src; u16* dst; int blk_end; };
struct CvtTab { CvtSeg s[6]; };

__global__ __launch_bounds__(256) void cvt_all(CvtTab t, int nseg) {
  const int blk = blockIdx.x;
  int k = 0;
  while (k < nseg - 1 && blk >= t.s[k].blk_end) k++;
  const int b0 = (k == 0) ? 0 : t.s[k-1].blk_end;
  const int off = (blk - b0) * 1024 + threadIdx.x * 4;
  float4 f = *(const float4*)(t.s[k].src + off);
  uint2 u;
  u.x = f2bf(f.x) | (f2bf(f.y) << 16);
  u.y = f2bf(f.z) | (f2bf(f.w) << 16);
  *(uint2*)(t.s[k].dst + off) = u;
}

// ---------------- bf16 GEMM: C = A[M,K] @ W[N,K]^T + bias, grouped outputs ----
// Weight rows grouped in chunks of 1024 (NG>1): block bn -> group bn>>3,
// output tensor t.o[g] (width 1024), bias t.b[g], epilogue scale t.sc[g].
struct GTab { u16* o[3]; const float* b[3]; float sc[3]; };

__device__ __forceinline__ void gl_lds16(const u16* g, u16* l) {
  __builtin_amdgcn_global_load_lds(
      (const __attribute__((address_space(1))) unsigned int*)g,
      (__attribute__((address_space(3))) unsigned int*)l, 16, 0, 0);
}

template<int RELU, int NG>
__global__ __launch_bounds__(256, 2) void gemm_bt(
    const u16* __restrict__ A,
    const u16* __restrict__ Bw,
    GTab t, int K, int N)
{
  __shared__ __align__(16) u16 As[128*32];
  __shared__ __align__(16) u16 Bs[128*32];
  const int tid  = threadIdx.x;
  const int lane = tid & 63;
  const int quad = lane >> 4;
  const int l16  = lane & 15;
  const int wave = tid >> 6;
  const int wm = (wave & 1) << 6;
  const int wn = (wave >> 1) << 6;
  const int bm = blockIdx.y << 7;
  const int bn = blockIdx.x << 7;

  const int grp = (NG > 1) ? ((int)blockIdx.x >> 3) : 0;
  u16* Cb = t.o[grp];
  const float* bias = t.b[grp];
  const float scale = t.sc[grp];
  const int ld = (NG > 1) ? 1024 : N;

  const int e0 = tid << 3;
  const int r0 = e0 >> 5;
  const int c0 = e0 & 31;
  const u16* a0 = A  + (size_t)(bm + r0)      * K + c0;
  const u16* a1 = A  + (size_t)(bm + r0 + 64) * K + c0;
  const u16* b0 = Bw + (size_t)(bn + r0)      * K + c0;
  const u16* b1 = Bw + (size_t)(bn + r0 + 64) * K + c0;

  f32x4 acc[4][4];
  #pragma unroll
  for (int i = 0; i < 4; i++)
    #pragma unroll
    for (int j = 0; j < 4; j++)
      acc[i][j] = (f32x4){0.f, 0.f, 0.f, 0.f};

  for (int k0 = 0; k0 < K; k0 += 32) {
    __syncthreads();
    gl_lds16(a0, As + e0);
    gl_lds16(a1, As + e0 + 2048);
    gl_lds16(b0, Bs + e0);
    gl_lds16(b1, Bs + e0 + 2048);
    a0 += 32; a1 += 32; b0 += 32; b1 += 32;
    __syncthreads();

    bf16x8 af[4], bfv[4];
    #pragma unroll
    for (int tt = 0; tt < 4; tt++) {
      af[tt]  = *(const bf16x8*)(As + ((wm + tt*16 + l16) << 5) + (quad << 3));
      bfv[tt] = *(const bf16x8*)(Bs + ((wn + tt*16 + l16) << 5) + (quad << 3));
    }
    #pragma unroll
    for (int mt = 0; mt < 4; mt++)
      #pragma unroll
      for (int nt = 0; nt < 4; nt++)
        acc[mt][nt] = __builtin_amdgcn_mfma_f32_16x16x32_bf16(af[mt], bfv[nt], acc[mt][nt], 0, 0, 0);
  }

  #pragma unroll
  for (int nt = 0; nt < 4; nt++) {
    const int col = bn + wn + nt*16 + l16;
    const int ocol = (NG > 1) ? (col & 1023) : col;
    const float bv = bias[ocol];
    #pragma unroll
    for (int mt = 0; mt < 4; mt++) {
      #pragma unroll
      for (int i = 0; i < 4; i++) {
        const int row = bm + wm + mt*16 + quad*4 + i;
        float v = (acc[mt][nt][i] + bv) * scale;
        if (RELU) v = fmaxf(v, 0.0f);
        Cb[(size_t)row * ld + ocol] = (u16)f2bf(v);
      }
    }
  }
}

// ---------------- V transpose: V[(l*B+b)][h*64+d] -> Vt[(b*16+h)*64+d][l] ----
__global__ __launch_bounds__(256) void transpose_v(
    const u16* __restrict__ V, u16* __restrict__ Vt)
{
  const int t = threadIdx.x;
  const int lane = t & 63;
  const int w = t >> 6;
  const int bh = blockIdx.y;
  const int b = bh >> 4, h = bh & 15;
  const int l = (blockIdx.x << 6) + lane;
  const size_t vrow = ((size_t)l * B_ + b) * E_ + h * 64;
  #pragma unroll
  for (int g = 0; g < 2; g++) {
    const int d0 = w * 8 + g * 32;
    uint4 u = *(const uint4*)(V + vrow + d0);
    u16 e[8];
    e[0] = u.x & 0xffff; e[1] = u.x >> 16;
    e[2] = u.y & 0xffff; e[3] = u.y >> 16;
    e[4] = u.z & 0xffff; e[5] = u.z >> 16;
    e[6] = u.w & 0xffff; e[7] = u.w >> 16;
    #pragma unroll
    for (int j = 0; j < 8; j++)
      Vt[(size_t)(bh * 64 + d0 + j) * S_ + l] = e[j];
  }
}

// ---------------- MFMA flash attention, 32 q-rows per wave ----------------
// Block 256 thr = 4 waves, Br=128 (wave w: rows wq=q0+w*32 .. +31, two
// 16-row halves), Bc=64. Q is pre-scaled by QK_SCALE (folded into GEMM).
// S^T = K @ Q^T: C lane q=l16, s=quad*4+reg (per 16-s tile). Softmax state
// per lane per half. P packed (truncating bf16) into per-wave LDS with row
// stride 80 elems (40 dwords): b64 writes and b128 reads are bank-floor.
// PV: A=P-frag, B=Vt-tile. O C/D: lane d=l16, q=quad*4+reg.
// O may alias Q (Q frags read first; blocks own disjoint rows).
template<int CAUSAL>
__global__ __launch_bounds__(256, 2) void attn_mfma(
    const u16* __restrict__ Q,
    const u16* __restrict__ Kg,
    const u16* __restrict__ Vt,
    u16* __restrict__ O,
    int Skv)
{
  __shared__ __align__(16) u16 Ks[64*72];
  __shared__ __align__(16) u16 Vs[64*72];
  __shared__ __align__(16) u16 Ps[4*2*16*80];
  const int tid  = threadIdx.x;
  const int lane = tid & 63;
  const int w    = tid >> 6;
  const int l16  = lane & 15;
  const int quad = lane >> 4;
  const int bh = blockIdx.y;
  const int b = bh >> 4, h = bh & 15;
  const int q0 = (CAUSAL ? ((int)gridDim.x - 1 - (int)blockIdx.x) : (int)blockIdx.x) << 7;
  const int wq = q0 + w*32;

  bf16x8 qf[2][2];
  #pragma unroll
  for (int h2 = 0; h2 < 2; h2++) {
    const size_t qoff = ((size_t)(wq + h2*16 + l16) * B_ + b) * E_ + h*64;
    qf[h2][0] = *(const bf16x8*)(Q + qoff + quad*8);
    qf[h2][1] = *(const bf16x8*)(Q + qoff + 32 + quad*8);
  }

  f32x4 oacc[2][4];
  #pragma unroll
  for (int h2 = 0; h2 < 2; h2++)
    #pragma unroll
    for (int i = 0; i < 4; i++) oacc[h2][i] = (f32x4){0.f,0.f,0.f,0.f};
  float mrun[2] = {-3e38f, -3e38f};
  float lsum[2] = {0.f, 0.f};

  const int sr = tid >> 3;            // 0..31
  const int sc = (tid & 7) << 3;      // 0..56
  const u16* pK0 = Kg + ((size_t)sr * B_ + b) * E_ + h*64 + sc;
  const u16* pK1 = pK0 + (size_t)32 * B_ * E_;
  const u16* pV0 = Vt + (size_t)(bh*64 + sr) * Skv + sc;
  const u16* pV1 = pV0 + (size_t)32 * Skv;
  const size_t kStep = (size_t)64 * B_ * E_;
  u16* ps = Ps + w * (2*16*80);

  const int send = CAUSAL ? (q0 + 128) : Skv;
  for (int s0 = 0; s0 < send; s0 += 64) {
    uint4 k0 = *(const uint4*)pK0;  pK0 += kStep;
    uint4 k1 = *(const uint4*)pK1;  pK1 += kStep;
    uint4 v0 = *(const uint4*)pV0;  pV0 += 64;
    uint4 v1 = *(const uint4*)pV1;  pV1 += 64;
    __syncthreads();                       // prior tile's LDS reads done
    *(uint4*)(Ks + sr*72 + sc)      = k0;
    *(uint4*)(Ks + (sr+32)*72 + sc) = k1;
    *(uint4*)(Vs + sr*72 + sc)      = v0;
    *(uint4*)(Vs + (sr+32)*72 + sc) = v1;
    __syncthreads();

    if (CAUSAL && s0 >= wq + 32) continue;   // wave-uniform: tile beyond rows

    // ---- S^T for both halves, K-frags shared ----
    f32x4 sacc[2][4];
    #pragma unroll
    for (int h2 = 0; h2 < 2; h2++)
      #pragma unroll
      for (int st = 0; st < 4; st++) sacc[h2][st] = (f32x4){0.f,0.f,0.f,0.f};
    #pragma unroll
    for (int kh = 0; kh < 2; kh++)
      #pragma unroll
      for (int st = 0; st < 4; st++) {
        bf16x8 kf = *(const bf16x8*)(Ks + (st*16 + l16)*72 + kh*32 + quad*8);
        sacc[0][st] = __builtin_amdgcn_mfma_f32_16x16x32_bf16(kf, qf[0][kh], sacc[0][st], 0, 0, 0);
        sacc[1][st] = __builtin_amdgcn_mfma_f32_16x16x32_bf16(kf, qf[1][kh], sacc[1][st], 0, 0, 0);
      }

    // ---- per-half online softmax ----
    #pragma unroll
    for (int h2 = 0; h2 < 2; h2++) {
      const int qa = wq + h2*16 + l16;
      float p[16];
      float mx = -3e38f;
      if (CAUSAL && (s0 + 63 > wq + h2*16)) {       // wave-uniform: partial tile
        #pragma unroll
        for (int st = 0; st < 4; st++)
          #pragma unroll
          for (int r = 0; r < 4; r++) {
            float sv = sacc[h2][st][r];
            sv = (s0 + st*16 + quad*4 + r <= qa) ? sv : -3e38f;
            p[st*4+r] = sv;
            mx = fmaxf(mx, sv);
          }
      } else {
        #pragma unroll
        for (int st = 0; st < 4; st++)
          #pragma unroll
          for (int r = 0; r < 4; r++) {
            float sv = sacc[h2][st][r];
            p[st*4+r] = sv;
            mx = fmaxf(mx, sv);
          }
      }
      mx = fmaxf(mx, __shfl_xor(mx, 16));
      mx = fmaxf(mx, __shfl_xor(mx, 32));
      const float mnew = fmaxf(mrun[h2], mx);
      const float alpha = exp2f(mrun[h2] - mnew);
      float rs = 0.f;
      #pragma unroll
      for (int i = 0; i < 16; i++) { p[i] = exp2f(p[i] - mnew); rs += p[i]; }
      rs += __shfl_xor(rs, 16);
      rs += __shfl_xor(rs, 32);
      lsum[h2] = lsum[h2] * alpha + rs;
      mrun[h2] = mnew;

      // pack P (truncating bf16 via v_perm) -> LDS, b64, bank-floor
      u16* pp = ps + h2*(16*80) + l16*80;
      #pragma unroll
      for (int st = 0; st < 4; st++) {
        uint2 d;
        d.x = __builtin_amdgcn_perm(__float_as_uint(p[st*4+1]), __float_as_uint(p[st*4+0]), 0x07060302u);
        d.y = __builtin_amdgcn_perm(__float_as_uint(p[st*4+3]), __float_as_uint(p[st*4+2]), 0x07060302u);
        *(uint2*)(pp + st*16 + quad*4) = d;
      }

      // rescale O accumulators (alpha uniform across quads per l16)
      #pragma unroll
      for (int r = 0; r < 4; r++) {
        const float ar = __shfl(alpha, (quad << 2) + r);
        #pragma unroll
        for (int dt = 0; dt < 4; dt++) oacc[h2][dt][r] *= ar;
      }
    }

    // ---- PV, V-frags shared between halves ----
    #pragma unroll
    for (int kh = 0; kh < 2; kh++) {
      bf16x8 pf0 = *(const bf16x8*)(ps +        l16*80 + (2*kh + (quad>>1))*16 + (quad&1)*8);
      bf16x8 pf1 = *(const bf16x8*)(ps + 16*80 + l16*80 + (2*kh + (quad>>1))*16 + (quad&1)*8);
      #pragma unroll
      for (int dt = 0; dt < 4; dt++) {
        bf16x8 vf = *(const bf16x8*)(Vs + (dt*16 + l16)*72 + kh*32 + quad*8);
        oacc[0][dt] = __builtin_amdgcn_mfma_f32_16x16x32_bf16(pf0, vf, oacc[0][dt], 0, 0, 0);
        oacc[1][dt] = __builtin_amdgcn_mfma_f32_16x16x32_bf16(pf1, vf, oacc[1][dt], 0, 0, 0);
      }
    }
  }

  // ---- epilogue ----
  #pragma unroll
  for (int h2 = 0; h2 < 2; h2++)
    #pragma unroll
    for (int r = 0; r < 4; r++) {
      const float li = 1.0f / __shfl(lsum[h2], (quad << 2) + r);
      const int qg = wq + h2*16 + quad*4 + r;
      const size_t orow = ((size_t)qg * B_ + b) * E_ + h*64;
      #pragma unroll
      for (int dt = 0; dt < 4; dt++)
        O[orow + dt*16 + l16] = (u16)f2bf(oacc[h2][dt][r] * li);
    }
}

// ---------------- residual add + LayerNorm ----------------
template<int RF32>
__global__ __launch_bounds__(256) void add_ln(
    const u16* __restrict__ X,
    const float* __restrict__ Rf, const u16* __restrict__ Rb,
    const float* __restrict__ g, const float* __restrict__ be,
    float* __restrict__ outF, u16* __restrict__ outB)
{
  const int row = blockIdx.x;
  const int tid = threadIdx.x;
  const size_t base = (size_t)row * E_;
  uint2 xu = *(const uint2*)(X + base + tid*4);
  float x0 = bflo(xu.x), x1 = bfhi(xu.x), x2 = bflo(xu.y), x3 = bfhi(xu.y);
  float r0, r1, r2, r3;
  if (RF32) {
    float4 rv = *(const float4*)(Rf + base + tid*4);
    r0 = rv.x; r1 = rv.y; r2 = rv.z; r3 = rv.w;
  } else {
    uint2 ru = *(const uint2*)(Rb + base + tid*4);
    r0 = bflo(ru.x); r1 = bfhi(ru.x); r2 = bflo(ru.y); r3 = bfhi(ru.y);
  }
  const float v0 = x0 + r0, v1 = x1 + r1, v2 = x2 + r2, v3 = x3 + r3;
  float s  = v0 + v1 + v2 + v3;
  float s2 = v0*v0 + v1*v1 + v2*v2 + v3*v3;
  #pragma unroll
  for (int off = 32; off >= 1; off >>= 1) {
    s  += __shfl_down(s,  off);
    s2 += __shfl_down(s2, off);
  }
  __shared__ float ps[4], ps2[4];
  const int wv = tid >> 6, lane = tid & 63;
  if (lane == 0) { ps[wv] = s; ps2[wv] = s2; }
  __syncthreads();
  const float ts  = ps[0] + ps[1] + ps[2] + ps[3];
  const float ts2 = ps2[0] + ps2[1] + ps2[2] + ps2[3];
  const float mu  = ts * (1.0f / E_);
  const float var = ts2 * (1.0f / E_) - mu * mu;
  const float rsq = rsqrtf(var + 1e-5f);
  float4 gv = *(const float4*)(g  + tid*4);
  float4 bv = *(const float4*)(be + tid*4);
  const float o0 = (v0 - mu) * rsq * gv.x + bv.x;
  const float o1 = (v1 - mu) * rsq * gv.y + bv.y;
  const float o2 = (v2 - mu) * rsq * gv.z + bv.z;
  const float o3 = (v3 - mu) * rsq * gv.w + bv.w;
  if (outF) {
    float4 ov; ov.x = o0; ov.y = o1; ov.z = o2; ov.w = o3;
    *(float4*)(outF + base + tid*4) = ov;
  }
  if (outB) {
    uint2 u;
    u.x = f2bf(o0) | (f2bf(o1) << 16);
    u.y = f2bf(o2) | (f2bf(o3) << 16);
    *(uint2*)(outB + base + tid*4) = u;
  }
}

// ---------------- driver ----------------
extern "C" void kernel_launch(void* const* d_in, const int* in_sizes, int n_in,
                              void* d_out, int out_size, void* d_ws, size_t ws_size,
                              hipStream_t stream) {
  (void)in_sizes; (void)n_in; (void)out_size; (void)ws_size;
  const float* tgt  = (const float*)d_in[0];
  const float* mem  = (const float*)d_in[1];
  const float* saWq = (const float*)d_in[3];  const float* sabq = (const float*)d_in[4];
  const float* saWk = (const float*)d_in[5];  const float* sabk = (const float*)d_in[6];
  const float* saWv = (const float*)d_in[7];  const float* sabv = (const float*)d_in[8];
  const float* saWo = (const float*)d_in[9];  const float* sabo = (const float*)d_in[10];
  const float* caWq = (const float*)d_in[11]; const float* cabq = (const float*)d_in[12];
  const float* caWk = (const float*)d_in[13]; const float* cabk = (const float*)d_in[14];
  const float* caWv = (const float*)d_in[15]; const float* cabv = (const float*)d_in[16];
  const float* caWo = (const float*)d_in[17]; const float* cabo = (const float*)d_in[18];
  const float* W1   = (const float*)d_in[19]; const float* b1   = (const float*)d_in[20];
  const float* W2   = (const float*)d_in[21]; const float* b2   = (const float*)d_in[22];
  const float* ln1g = (const float*)d_in[23]; const float* ln1b = (const float*)d_in[24];
  const float* ln2g = (const float*)d_in[25]; const float* ln2b = (const float*)d_in[26];
  const float* ln3g = (const float*)d_in[27]; const float* ln3b = (const float*)d_in[28];
  float* out = (float*)d_out;

  // Workspace (16MB slots), peak 104 MB (known good):
  //  A: tgt_bf16 -> x1 -> x2    Cq: q / attn-out (in-place)   Bm: memory_bf16
  //  Dk: k                      Ev: v                          Ff: Vt -> gemm out
  //  wS: 8MB weight staging (refilled 4x)     hb = Cq..Ev (64MB FFN hidden)
  char* wsp = (char*)d_ws;
  const size_t MB16 = (size_t)16 * 1024 * 1024;
  u16* A  = (u16*)(wsp + 0 * MB16);
  u16* Cq = (u16*)(wsp + 1 * MB16);
  u16* Bm = (u16*)(wsp + 2 * MB16);
  u16* Dk = (u16*)(wsp + 3 * MB16);
  u16* Ev = (u16*)(wsp + 4 * MB16);
  u16* Ff = (u16*)(wsp + 5 * MB16);
  u16* wS = (u16*)(wsp + 6 * MB16);
  u16* hb = Cq;
  const int MEG = 1024 * 1024;

  dim3 blk(256);
  dim3 gQKV(24, 64);          // N=3072
  dim3 gKV(16, 64);           // N=2048
  dim3 g8(8, 64);             // N=1024
  dim3 g32(32, 64);           // N=4096
  dim3 ga(L_/128, B_*H_);
  dim3 gt(S_/64, B_*H_);

  auto gt1 = [](u16* o, const float* bi, float s) {
    GTab t{}; t.o[0]=o; t.o[1]=o; t.o[2]=o; t.b[0]=bi; t.b[1]=bi; t.b[2]=bi;
    t.sc[0]=s; t.sc[1]=s; t.sc[2]=s; return t;
  };

  // ---- cvt1: inputs + self-attn weights ----
  {
    CvtTab t{};
    t.s[0] = {tgt,  A,        8192};
    t.s[1] = {mem,  Bm,       16384};
    t.s[2] = {saWq, wS,       17408};
    t.s[3] = {saWk, wS + MEG,   18432};
    t.s[4] = {saWv, wS + 2*MEG, 19456};
    t.s[5] = {saWo, wS + 3*MEG, 20480};
    cvt_all<<<20480, blk, 0, stream>>>(t, 6);
  }

  // ---- self-attention ----
  {
    GTab t{};
    t.o[0]=Cq; t.o[1]=Dk; t.o[2]=Ev;
    t.b[0]=sabq; t.b[1]=sabk; t.b[2]=sabv;
    t.sc[0]=QK_SCALE; t.sc[1]=1.f; t.sc[2]=1.f;
    gemm_bt<0,3><<<gQKV, blk, 0, stream>>>(A, wS, t, E_, 3*E_);
  }
  transpose_v<<<gt, blk, 0, stream>>>(Ev, Ff);
  attn_mfma<1><<<ga, blk, 0, stream>>>(Cq, Dk, Ff, Cq, S_);
  gemm_bt<0,1><<<g8, blk, 0, stream>>>(Cq, wS + 3*MEG, gt1(Ff, sabo, 1.f), E_, E_);
  add_ln<1><<<M_, blk, 0, stream>>>(Ff, tgt, nullptr, ln1g, ln1b, nullptr, A);

  // ---- cvt2: cross-attn weights ----
  {
    CvtTab t{};
    t.s[0] = {caWq, wS,        1024};
    t.s[1] = {caWk, wS + MEG,    2048};
    t.s[2] = {caWv, wS + 2*MEG,  3072};
    t.s[3] = {caWo, wS + 3*MEG,  4096};
    cvt_all<<<4096, blk, 0, stream>>>(t, 4);
  }

  // ---- cross-attention ----
  gemm_bt<0,1><<<g8, blk, 0, stream>>>(A, wS, gt1(Cq, cabq, QK_SCALE), E_, E_);
  {
    GTab t{};
    t.o[0]=Dk; t.o[1]=Ev; t.o[2]=Ev;
    t.b[0]=cabk; t.b[1]=cabv; t.b[2]=cabv;
    t.sc[0]=1.f; t.sc[1]=1.f; t.sc[2]=1.f;
    gemm_bt<0,2><<<gKV, blk, 0, stream>>>(Bm, wS + MEG, t, E_, 2*E_);
  }
  transpose_v<<<gt, blk, 0, stream>>>(Ev, Ff);
  attn_mfma<0><<<ga, blk, 0, stream>>>(Cq, Dk, Ff, Cq, S_);
  gemm_bt<0,1><<<g8, blk, 0, stream>>>(Cq, wS + 3*MEG, gt1(Ff, cabo, 1.f), E_, E_);
  add_ln<0><<<M_, blk, 0, stream>>>(Ff, nullptr, A, ln2g, ln2b, nullptr, A);

  // ---- FFN ----
  {
    CvtTab t{};
    t.s[0] = {W1, wS, 4096};
    cvt_all<<<4096, blk, 0, stream>>>(t, 1);
  }
  gemm_bt<1,1><<<g32, blk, 0, stream>>>(A, wS, gt1(hb, b1, 1.f), E_, FF_);
  {
    CvtTab t{};
    t.s[0] = {W2, wS, 4096};
    cvt_all<<<4096, blk, 0, stream>>>(t, 1);
  }
  gemm_bt<0,1><<<g8, blk, 0, stream>>>(hb, wS, gt1(Ff, b2, 1.f), FF_, E_);
  add_ln<0><<<M_, blk, 0, stream>>>(Ff, nullptr, A, ln3g, ln3b, out, nullptr);
}